// Round 8
// baseline (244.959 us; speedup 1.0000x reference)
//
#include <hip/hip_runtime.h>
#include <hip/hip_bf16.h>
#include <math.h>

// Problem constants
#define MM 12544   // 64 * 196 patches
#define KK 768     // 16*16*3
#define NN 768     // embedding dim
#define BM 64
#define BN 256
#define NKS 24             // KK/32 k-steps
#define MT 196             // MM/BM
#define NT 3               // NN/BN
#define N64 12             // NN/64

// Persistent work-queue: one kernel does W-pack, A-pack, then GEMM, with
// per-panel readiness flags so GEMM tiles start as soon as their A-panel
// (plus W) is packed -- pack overlaps gemm instead of serializing.
#define W_ITEMS 288                       // one per (n64, ks)
#define A_ITEMS (MT * 4)                  // 784: one per (mt, row-quarter)
#define PACK_ITEMS (W_ITEMS + A_ITEMS)    // 1072
#define G_ITEMS (MT * NT)                 // 588
#define TOTAL_ITEMS (PACK_ITEMS + G_ITEMS)// 1660
#define NBLK_PERS 768                     // 3 blocks/CU

#define FRAG_BYTES 1024                   // 64 lanes x 16B
#define KSTRIDE (4 * FRAG_BYTES)          // per-ks: 4 frags = 4KB
#define PANEL_BYTES (NKS * KSTRIDE)       // 96KB per 64-row/col panel

#define APACK_BYTES ((size_t)MM * KK * 2) // 19,267,584
#define WPACK_BYTES ((size_t)NN * KK * 2) //  1,179,648
#define CTRS_OFF (APACK_BYTES + WPACK_BYTES)

typedef __bf16 v8bf __attribute__((ext_vector_type(8)));
typedef float  v4f  __attribute__((ext_vector_type(4)));

// Fast GELU: 0.5x(1+tanh(0.79788456(x+0.044715x^3))) = x * E/(E+1), E=e^{2t}.
__device__ __forceinline__ float gelu_fast(float x) {
    float t2 = 1.5957691216057308f * x * (1.0f + 0.044715f * x * x);  // 2t
    float e  = __expf(t2);
    float r  = __builtin_amdgcn_rcpf(e + 1.0f);
    return x - x * r;   // x*(1 - 1/(E+1)) = x*E/(E+1)
}

// ---------------------------------------------------------------------------
// Persistent fused kernel. Item map:
//   it in [0,288)            : W-pack item (= R5 wpack block)
//   it in [288,1072)         : A-pack item (= R7 read-once block), a=it-288,
//                              mt=a>>2, quarter c=a&3; flags adone[mt]++
//   it in [1072,1660)        : GEMM tile g=it-1072, mt=g/3, nt=g%3;
//                              waits wdone==288 && adone[mt]==4 (spin+sleep)
// First item = blockIdx.x (no atomic storm); rest via queue atomicAdd.
// Deadlock-free for ANY dispatch order: gemm items are grabbed only after
// all pack items are grabbed, and grabbed pack items belong to resident,
// never-waiting blocks.
// ---------------------------------------------------------------------------
__global__ __launch_bounds__(256, 3) void fused_all(const float* __restrict__ img,
                                                    const float* __restrict__ w,
                                                    const float* __restrict__ bias,
                                                    float* __restrict__ out,
                                                    __hip_bfloat16* __restrict__ apack,
                                                    __hip_bfloat16* __restrict__ wpack,
                                                    unsigned int* __restrict__ ctrs) {
    unsigned int* queue = ctrs;        // grabs beyond the first NBLK_PERS
    unsigned int* wdone = ctrs + 1;    // 0..288
    unsigned int* adone = ctrs + 2;    // [196], each 0..4

    __shared__ int s_item;
    const int tid = threadIdx.x;

    int it = blockIdx.x;               // first item, no atomic
    for (;;) {
        if (it >= TOTAL_ITEMS) break;  // block-uniform
        unsigned int* fptr = nullptr;  // completion flag for pack items

        if (it < W_ITEMS) {
            // ---- W-pack: chunk ((n64*24+ks)*4+fi)*64+l holds
            //      W[ks*32+(l>>4)*8 .. +8][n64*64+fi*16+(l&15)] ----
            const int l   = tid & 63;
            const int fi  = tid >> 6;
            const int n64 = it / NKS;
            const int ks  = it - n64 * NKS;
            const int col = n64 * 64 + fi * 16 + (l & 15);
            const int k0  = ks * 32 + (l >> 4) * 8;
            union { __hip_bfloat16 hh[8]; uint4 uu; } o;
#pragma unroll
            for (int j = 0; j < 8; j++)
                o.hh[j] = __float2bfloat16(w[(size_t)(k0 + j) * NN + col]);
            ((uint4*)wpack)[(size_t)((n64 * NKS + ks) * 4 + fi) * 64 + l] = o.uu;
            fptr = wdone;
        } else if (it < PACK_ITEMS) {
            // ---- A-pack (read-once): thread (r=tid&63, il=tid>>6) reads one
            //      48-float patch-row run, emits 6 bf16 8-groups ----
            const int a   = it - W_ITEMS;
            const int mt  = a >> 2;
            const int c   = a & 3;
            const int r   = tid & 63;
            const int il  = tid >> 6;
            const int i   = c * 4 + il;        // patch row 0..15
            const int m   = mt * 64 + r;
            const int b   = m / 196;
            const int pm  = m - b * 196;
            const int pr  = pm / 14;
            const int pc  = pm - pr * 14;
            const float* src = img + (size_t)(((b * 224 + pr * 16 + i) * 224 + pc * 16) * 3);
            float4 f[12];
#pragma unroll
            for (int ld = 0; ld < 12; ld++) f[ld] = ((const float4*)src)[ld];
            const int fi   = r >> 4;
            const int l_lo = r & 15;
            uint4* dst = (uint4*)apack + ((size_t)(mt * 24) * 4 + fi) * 64 + l_lo;
#pragma unroll
            for (int j = 0; j < 6; j++) {
                const int G  = i * 6 + j;      // 8-group index 0..95
                const int ks = G >> 2;
                const int lh = G & 3;
                union { __hip_bfloat16 hh[8]; uint4 uu; } o;
                o.hh[0] = __float2bfloat16(f[2*j].x);   o.hh[1] = __float2bfloat16(f[2*j].y);
                o.hh[2] = __float2bfloat16(f[2*j].z);   o.hh[3] = __float2bfloat16(f[2*j].w);
                o.hh[4] = __float2bfloat16(f[2*j+1].x); o.hh[5] = __float2bfloat16(f[2*j+1].y);
                o.hh[6] = __float2bfloat16(f[2*j+1].z); o.hh[7] = __float2bfloat16(f[2*j+1].w);
                dst[(size_t)ks * 256 + lh * 16] = o.uu;
            }
            fptr = &adone[mt];
        } else {
            // ---- GEMM tile (R5 body): 64x256, 4 waves 1x4 in N,
            //      LDS-free, 2-deep register prefetch ----
            const int g  = it - PACK_ITEMS;
            const int mt = g / 3;
            const int nt = g - mt * 3;

            if (tid == 0) {
                while (__hip_atomic_load(wdone, __ATOMIC_RELAXED,
                                         __HIP_MEMORY_SCOPE_AGENT) < W_ITEMS)
                    __builtin_amdgcn_s_sleep(2);
                while (__hip_atomic_load(&adone[mt], __ATOMIC_RELAXED,
                                         __HIP_MEMORY_SCOPE_AGENT) < 4)
                    __builtin_amdgcn_s_sleep(2);
            }
            __syncthreads();
            __threadfence();               // acquire: invalidate stale L2 lines

            const int lane = tid & 63;
            const int wave = tid >> 6;
            const int col  = lane & 15;
            const int quad = lane >> 4;

            const char* pA = (const char*)apack + (size_t)mt * PANEL_BYTES + lane * 16;
            const char* pB = (const char*)wpack + (size_t)(nt * 4 + wave) * PANEL_BYTES + lane * 16;

            v4f acc[4][4];
            const v4f vzero = {0.f, 0.f, 0.f, 0.f};
#pragma unroll
            for (int aa = 0; aa < 4; aa++)
#pragma unroll
                for (int cc = 0; cc < 4; cc++) acc[aa][cc] = vzero;

            v8bf aR[2][4], bR[2][4];
#pragma unroll
            for (int mi = 0; mi < 4; mi++) {
                aR[0][mi] = *(const v8bf*)(pA + mi * FRAG_BYTES);
                aR[1][mi] = *(const v8bf*)(pA + KSTRIDE + mi * FRAG_BYTES);
            }
#pragma unroll
            for (int ni = 0; ni < 4; ni++) {
                bR[0][ni] = *(const v8bf*)(pB + ni * FRAG_BYTES);
                bR[1][ni] = *(const v8bf*)(pB + KSTRIDE + ni * FRAG_BYTES);
            }
#pragma unroll
            for (int ks = 0; ks < NKS; ks++) {
                const int cur = ks & 1;
                __builtin_amdgcn_s_setprio(1);
#pragma unroll
                for (int mi = 0; mi < 4; mi++)
#pragma unroll
                    for (int ni = 0; ni < 4; ni++)
                        acc[mi][ni] = __builtin_amdgcn_mfma_f32_16x16x32_bf16(
                            aR[cur][mi], bR[cur][ni], acc[mi][ni], 0, 0, 0);
                __builtin_amdgcn_s_setprio(0);
                if (ks + 2 < NKS) {
                    const char* qA = pA + (size_t)(ks + 2) * KSTRIDE;
                    const char* qB = pB + (size_t)(ks + 2) * KSTRIDE;
#pragma unroll
                    for (int mi = 0; mi < 4; mi++)
                        aR[cur][mi] = *(const v8bf*)(qA + mi * FRAG_BYTES);
#pragma unroll
                    for (int ni = 0; ni < 4; ni++)
                        bR[cur][ni] = *(const v8bf*)(qB + ni * FRAG_BYTES);
                }
            }
            // epilogue: bias + fast GELU, coalesced fp32 stores
#pragma unroll
            for (int ni = 0; ni < 4; ni++) {
                int n    = nt * BN + wave * 64 + ni * 16 + col;
                float bv = bias[n];
#pragma unroll
                for (int mi = 0; mi < 4; mi++) {
                    int rowb = mt * BM + mi * 16 + quad * 4;
                    float* po = out + (size_t)rowb * NN + n;
#pragma unroll
                    for (int rg = 0; rg < 4; rg++) {
                        float x = acc[mi][ni][rg] + bv;
                        po[(size_t)rg * NN] = gelu_fast(x);
                    }
                }
            }
        }

        // ---- loop tail: flag pack completion, grab next item ----
        __syncthreads();                   // drains this block's stores (vmcnt0)
        if (tid == 0) {
            if (fptr) {
                __threadfence();           // release: write back L2 to coherent pt
                atomicAdd(fptr, 1u);       // device-scope RMW
            }
            s_item = NBLK_PERS + (int)atomicAdd(queue, 1u);
        }
        __syncthreads();
        it = s_item;
    }
}

extern "C" void kernel_launch(void* const* d_in, const int* in_sizes, int n_in,
                              void* d_out, int out_size, void* d_ws, size_t ws_size,
                              hipStream_t stream) {
    const float* img   = (const float*)d_in[0];   // [64,224,224,3]
    const float* wproj = (const float*)d_in[1];   // [768,768]
    const float* bias  = (const float*)d_in[2];   // [768]
    float* out = (float*)d_out;                   // [64,196,768]

    __hip_bfloat16* apack = (__hip_bfloat16*)d_ws;
    __hip_bfloat16* wpack = (__hip_bfloat16*)((char*)d_ws + APACK_BYTES);
    unsigned int*   ctrs  = (unsigned int*)((char*)d_ws + CTRS_OFF);
    // ws need: 20,447,232 + 1KB counters

    hipMemsetAsync(ctrs, 0, 1024, stream);
    fused_all<<<dim3(NBLK_PERS), dim3(256), 0, stream>>>(
        img, wproj, bias, out, apack, wpack, ctrs);
}

// Round 9
// 118.089 us; speedup vs baseline: 2.0744x; 2.0744x over previous
//
#include <hip/hip_runtime.h>
#include <hip/hip_bf16.h>
#include <math.h>

// Problem constants
#define MM 12544   // 64 * 196 patches
#define KK 768     // 16*16*3
#define NN 768     // embedding dim
// LDS-free GEMM: BM=64, BN=256, 4 waves 1x4 in N (each wave 64x64 output).
// A and B are pre-packed into FRAGMENT-LANE-MAJOR layout: one MFMA fragment
// (16 rows/cols x 32 k, 64 lanes x 16B) = one contiguous 1KB chunk.
// The GEMM loads fragments global->register directly: no LDS, no barriers,
// no forced vmcnt(0) drains. TWO-deep register prefetch: fragment loads for
// ks+2 issue after the MFMA cluster of ks (~2 MFMA clusters in flight before
// their vmcnt wait -> covers L2 latency). This is the session-best R5
// structure, re-landed verbatim after R6-R8 structural experiments all
// regressed (pack-swizzle imbalance; persistent-fusion regalloc collapse).
#define BM 64
#define BN 256
#define NKS 24             // KK / 32 k-steps
#define MT 196             // MM/BM
#define NT 3               // NN/BN
#define N64 12             // NN/64 wave-column groups

#define A_BLOCKS (MT * NKS)    // 4704
#define W_BLOCKS (N64 * NKS)   // 288
#define FRAG_BYTES 1024        // 64 lanes x 16B
#define KSTRIDE (4 * FRAG_BYTES)          // per-ks: 4 frags = 4KB
#define PANEL_BYTES (NKS * KSTRIDE)       // 96KB per 64-row/col panel

typedef __bf16 v8bf __attribute__((ext_vector_type(8)));
typedef float  v4f  __attribute__((ext_vector_type(4)));

// ---------------------------------------------------------------------------
// Pack: im2col A and transpose W into fragment-lane-major bf16 chunks.
// A chunk id: ((mt*24 + ks)*4 + mi)*64 + lane ; lane l = (k8=l>>4, row=l&15)
//   holds A[mt*64 + mi*16 + (l&15)][ks*32 + (l>>4)*8 .. +8]
// W chunk id: ((n64*24 + ks)*4 + ni)*64 + lane
//   holds W[ks*32 + (l>>4)*8 .. +8][n64*64 + ni*16 + (l&15)]
// Writes are perfectly coalesced (chunk addr = base + tid*16).
// ---------------------------------------------------------------------------
__global__ __launch_bounds__(256) void pack_kernel(const float* __restrict__ img,
                                                   const float* __restrict__ w,
                                                   __hip_bfloat16* __restrict__ apack,
                                                   __hip_bfloat16* __restrict__ wpack) {
    const int tid  = threadIdx.x;
    const int l    = tid & 63;
    const int fi   = tid >> 6;      // mi or ni (0..3)
    const int l_lo = l & 15;        // row / col within fragment
    const int l_hi = l >> 4;        // 8-k group within 32

    union { __hip_bfloat16 h[8]; uint4 u; } o;

    if (blockIdx.x < A_BLOCKS) {
        const int bid = blockIdx.x;
        const int mt  = bid / NKS;
        const int ks  = bid - mt * NKS;
        const int m   = mt * 64 + fi * 16 + l_lo;   // global patch index
        const int k0  = ks * 32 + l_hi * 8;         // k within 768
        const int b   = m / 196;
        const int pm  = m - b * 196;
        const int pr  = pm / 14;
        const int pc  = pm - pr * 14;
        const int i   = k0 / 48;                    // row within patch
        const int rem = k0 - i * 48;                // 8-aligned, <=40
        const float* src = img + (size_t)(((b * 224 + pr * 16 + i) * 224 + pc * 16) * 3 + rem);
        float4 f0 = *(const float4*)src;            // 16B-aligned (rem mult of 8 floats)
        float4 f1 = *(const float4*)(src + 4);
        o.h[0] = __float2bfloat16(f0.x); o.h[1] = __float2bfloat16(f0.y);
        o.h[2] = __float2bfloat16(f0.z); o.h[3] = __float2bfloat16(f0.w);
        o.h[4] = __float2bfloat16(f1.x); o.h[5] = __float2bfloat16(f1.y);
        o.h[6] = __float2bfloat16(f1.z); o.h[7] = __float2bfloat16(f1.w);
        ((uint4*)apack)[(size_t)((mt * NKS + ks) * 4 + fi) * 64 + l] = o.u;
    } else {
        const int bid = blockIdx.x - A_BLOCKS;
        const int n64 = bid / NKS;
        const int ks  = bid - n64 * NKS;
        const int col = n64 * 64 + fi * 16 + l_lo;
        const int k0  = ks * 32 + l_hi * 8;
        float f[8];
#pragma unroll
        for (int j = 0; j < 8; j++) f[j] = w[(size_t)(k0 + j) * NN + col];
#pragma unroll
        for (int j = 0; j < 8; j++) o.h[j] = __float2bfloat16(f[j]);
        ((uint4*)wpack)[(size_t)((n64 * NKS + ks) * 4 + fi) * 64 + l] = o.u;
    }
}

// Fast GELU: 0.5x(1+tanh(0.79788456(x+0.044715x^3))) = x * E/(E+1), E=e^{2t}.
// v_exp + v_rcp; max deviation from exact erf-GELU ~3e-3 << 0.103 threshold.
__device__ __forceinline__ float gelu_fast(float x) {
    float t2 = 1.5957691216057308f * x * (1.0f + 0.044715f * x * x);  // 2t
    float e  = __expf(t2);
    float r  = __builtin_amdgcn_rcpf(e + 1.0f);
    return x - x * r;   // x*(1 - 1/(E+1)) = x*E/(E+1)
}

// ---------------------------------------------------------------------------
// LDS-free MFMA GEMM + bias + fast GELU, 2-deep register pipeline.
// 64x256 tile, 4 waves 1x4 in N. A-frags 4x-duplicated across waves -> L1
// hits (same addresses across waves); B-frags wave-private. XCD chunked
// swizzle (bijective for 588): the 3 nt-blocks of one mt share an XCD's L2.
// ---------------------------------------------------------------------------
__global__ __launch_bounds__(256, 3) void gemm_reg(const __hip_bfloat16* __restrict__ apack,
                                                   const __hip_bfloat16* __restrict__ wpack,
                                                   const float* __restrict__ bias,
                                                   float* __restrict__ out) {
    const int h   = blockIdx.x;
    const int xcd = h & 7;
    const int jj  = h >> 3;
    const int u   = (xcd < 4 ? xcd * 74 : 296 + (xcd - 4) * 73) + jj;
    const int nt  = u % 3;
    const int mt  = u / 3;

    const int tid  = threadIdx.x;
    const int lane = tid & 63;
    const int wave = tid >> 6;
    const int col  = lane & 15;
    const int quad = lane >> 4;

    const char* pA = (const char*)apack + (size_t)mt * PANEL_BYTES + lane * 16;
    const char* pB = (const char*)wpack + (size_t)(nt * 4 + wave) * PANEL_BYTES + lane * 16;

    v4f acc[4][4];
    const v4f vzero = {0.f, 0.f, 0.f, 0.f};
#pragma unroll
    for (int a = 0; a < 4; a++)
#pragma unroll
        for (int c = 0; c < 4; c++) acc[a][c] = vzero;

    v8bf aR[2][4], bR[2][4];
    // ---- prologue: preload ks = 0 (buf0) and ks = 1 (buf1) ----
#pragma unroll
    for (int mi = 0; mi < 4; mi++) {
        aR[0][mi] = *(const v8bf*)(pA + mi * FRAG_BYTES);
        aR[1][mi] = *(const v8bf*)(pA + KSTRIDE + mi * FRAG_BYTES);
    }
#pragma unroll
    for (int ni = 0; ni < 4; ni++) {
        bR[0][ni] = *(const v8bf*)(pB + ni * FRAG_BYTES);
        bR[1][ni] = *(const v8bf*)(pB + KSTRIDE + ni * FRAG_BYTES);
    }

    // ---- main loop: MFMA(ks) then issue loads for ks+2 into buf[ks&1].
    // Loads sit in flight across ~2 MFMA clusters before their vmcnt wait.
#pragma unroll
    for (int ks = 0; ks < NKS; ks++) {
        const int cur = ks & 1;          // literal after full unroll
        __builtin_amdgcn_s_setprio(1);
#pragma unroll
        for (int mi = 0; mi < 4; mi++)
#pragma unroll
            for (int ni = 0; ni < 4; ni++)
                acc[mi][ni] = __builtin_amdgcn_mfma_f32_16x16x32_bf16(
                    aR[cur][mi], bR[cur][ni], acc[mi][ni], 0, 0, 0);
        __builtin_amdgcn_s_setprio(0);
        if (ks + 2 < NKS) {
            const char* qA = pA + (size_t)(ks + 2) * KSTRIDE;
            const char* qB = pB + (size_t)(ks + 2) * KSTRIDE;
#pragma unroll
            for (int mi = 0; mi < 4; mi++)
                aR[cur][mi] = *(const v8bf*)(qA + mi * FRAG_BYTES);
#pragma unroll
            for (int ni = 0; ni < 4; ni++)
                bR[cur][ni] = *(const v8bf*)(qB + ni * FRAG_BYTES);
        }
    }

    // ---- epilogue: bias + fast GELU, coalesced fp32 stores ----
#pragma unroll
    for (int ni = 0; ni < 4; ni++) {
        int n    = nt * BN + wave * 64 + ni * 16 + col;
        float bv = bias[n];
#pragma unroll
        for (int mi = 0; mi < 4; mi++) {
            int rowb = mt * BM + mi * 16 + quad * 4;
            float* po = out + (size_t)rowb * NN + n;
#pragma unroll
            for (int rg = 0; rg < 4; rg++) {
                float x = acc[mi][ni][rg] + bv;
                po[(size_t)rg * NN] = gelu_fast(x);
            }
        }
    }
}

extern "C" void kernel_launch(void* const* d_in, const int* in_sizes, int n_in,
                              void* d_out, int out_size, void* d_ws, size_t ws_size,
                              hipStream_t stream) {
    const float* img   = (const float*)d_in[0];   // [64,224,224,3]
    const float* wproj = (const float*)d_in[1];   // [768,768]
    const float* bias  = (const float*)d_in[2];   // [768]
    float* out = (float*)d_out;                   // [64,196,768]

    __hip_bfloat16* apack = (__hip_bfloat16*)d_ws;                        // 19,267,584 B
    __hip_bfloat16* wpack = (__hip_bfloat16*)((char*)d_ws + (size_t)MM * KK * 2);
    // total ws need: 20,447,232 B

    pack_kernel<<<dim3(A_BLOCKS + W_BLOCKS), dim3(256), 0, stream>>>(
        img, wproj, apack, wpack);
    gemm_reg<<<dim3(MT * NT), dim3(256), 0, stream>>>(apack, wpack, bias, out);
}